// Round 4
// baseline (481.631 us; speedup 1.0000x reference)
//
#include <hip/hip_runtime.h>
#include <math.h>

#define KCLS  50000
#define KP    50048   // KCLS padded to multiple of 128 for the GEMM class dim
#define DIM   128
#define BATCH 1024
#define MAXD  16

#define NBLK_N   (KP / 128)       // 391 column blocks in the GEMM
#define NBP      (NBLK_N * 2)     // 782 partial (m,s) pairs per row (2 col-waves/block)
#define CLS_BLOCKS (KP / 4)       // 12512 aw blocks (4 classes per 256-thr block)
#define XB_BLOCKS  (BATCH * DIM / 1024)  // 128 folded x-conversion blocks

typedef __attribute__((ext_vector_type(8))) short short8;
typedef __attribute__((ext_vector_type(4))) float floatx4;

// round-to-nearest-even float -> bf16 bits (inputs are finite)
__device__ __forceinline__ unsigned short f2bf(float f) {
    unsigned u = __float_as_uint(f);
    u += 0x7fffu + ((u >> 16) & 1u);
    return (unsigned short)(u >> 16);
}

// ---------------------------------------------------------------------------
// Kernel 1: added_weights[k] = weights[k] + sum_{p<len} weights[path_idx[k,p]]
// ONE class per 64-lane wave (float2/lane = one 512B row) so the path loop
// trip count is wave-uniform. 4-deep unrolled path loop: 4 row-loads in
// flight (avg len = 7.5, so main loop runs ~2 iters with full MLP).
// Emits bf16 copy (pad rows zeroed). Blocks >= CLS_BLOCKS convert x -> bf16.
__global__ __launch_bounds__(256) void aw_kernel(
    const float* __restrict__ weights, const int* __restrict__ path_idx,
    const int* __restrict__ path_len, float* __restrict__ aw,
    unsigned short* __restrict__ awb,
    const float* __restrict__ x, unsigned short* __restrict__ xb)
{
    int t = threadIdx.x;

    if (blockIdx.x >= CLS_BLOCKS) {   // folded x fp32->bf16 (131072 elements)
        int i = ((blockIdx.x - CLS_BLOCKS) * 256 + t) * 4;
        float4 v = *(const float4*)(x + i);
        ushort4 hv = { f2bf(v.x), f2bf(v.y), f2bf(v.z), f2bf(v.w) };
        *(ushort4*)(xb + i) = hv;
        return;
    }

    int w = t >> 6, lane = t & 63;
    int k = blockIdx.x * 4 + w;
    int col = lane * 2;

    if (k >= KCLS) {                  // zero-fill bf16 pad rows [KCLS, KP)
        ushort2 z; z.x = 0; z.y = 0;
        *(ushort2*)(awb + (size_t)k * DIM + col) = z;
        return;
    }

    float2 acc = *(const float2*)(weights + (size_t)k * DIM + col);
    int len = path_len[k];
    const int* pp = path_idx + (size_t)k * MAXD;

    int p = 0;
    for (; p + 4 <= len; p += 4) {    // 4 row loads in flight
        int i0 = pp[p], i1 = pp[p + 1], i2 = pp[p + 2], i3 = pp[p + 3];
        float2 a = *(const float2*)(weights + (size_t)i0 * DIM + col);
        float2 b = *(const float2*)(weights + (size_t)i1 * DIM + col);
        float2 c = *(const float2*)(weights + (size_t)i2 * DIM + col);
        float2 d = *(const float2*)(weights + (size_t)i3 * DIM + col);
        acc.x += (a.x + b.x) + (c.x + d.x);
        acc.y += (a.y + b.y) + (c.y + d.y);
    }
    for (; p < len; ++p) {
        int i0 = pp[p];
        float2 a = *(const float2*)(weights + (size_t)i0 * DIM + col);
        acc.x += a.x;
        acc.y += a.y;
    }

    *(float2*)(aw + (size_t)k * DIM + col) = acc;   // output (never re-read)
    ushort2 hv; hv.x = f2bf(acc.x); hv.y = f2bf(acc.y);
    *(ushort2*)(awb + (size_t)k * DIM + col) = hv;
}

// ---------------------------------------------------------------------------
// Kernel 2: logits = Xb · Wb^T via bf16 MFMA 16x16x32, SWAPPED operands:
// A = W-tile (classes = C rows), B = X-tile (batch = C cols). C/D layout
// (col=lane&15, row=quad*4+reg) then gives each lane 4 CONSECUTIVE classes
// in one batch row -> floatx4 nontemporal stores (4x fewer store instrs than
// the batch-major layout, and logits are pure streaming output).
// Grid: x = M-blocks (8, fastest) so the 8 blocks sharing one Wb tile
// dispatch back-to-back -> Wb fetched from HBM ~once (12.8 MB not 102 MB).
// PART: fused LSE partials; per batch row the wave reduce is 16 lane-local
// values + 2 shfl_xor (across quads).
template<bool PART>
__global__ __launch_bounds__(256) void gemm_kernel(
    const unsigned short* __restrict__ Xb,   // [BATCH][DIM] bf16
    const unsigned short* __restrict__ Wb,   // [KP][DIM] bf16
    float* __restrict__ logits,              // [BATCH][KCLS]
    float2* __restrict__ part)               // [BATCH][NBP] (m, sumexp)
{
    int tid = threadIdx.x;
    int wave = tid >> 6, lane = tid & 63;
    int r = lane & 15, quad = lane >> 4;
    int m0 = blockIdx.x * 128 + (wave >> 1) * 64;   // batch rows
    int n0 = blockIdx.y * 128 + (wave & 1) * 64;    // class cols

    const unsigned short* wp = Wb + (size_t)(n0 + r) * DIM + quad * 8;  // A
    const unsigned short* xp = Xb + (size_t)(m0 + r) * DIM + quad * 8;  // B

    floatx4 acc[4][4];   // [class-tile i][batch-tile j]
    #pragma unroll
    for (int i = 0; i < 4; ++i)
        #pragma unroll
        for (int j = 0; j < 4; ++j)
            acc[i][j] = (floatx4){0.f, 0.f, 0.f, 0.f};

    #pragma unroll
    for (int kk = 0; kk < 4; ++kk) {
        short8 a[4], b[4];
        #pragma unroll
        for (int i = 0; i < 4; ++i)
            a[i] = *(const short8*)(wp + (size_t)(i * 16) * DIM + kk * 32);
        #pragma unroll
        for (int j = 0; j < 4; ++j)
            b[j] = *(const short8*)(xp + (size_t)(j * 16) * DIM + kk * 32);
        #pragma unroll
        for (int i = 0; i < 4; ++i)
            #pragma unroll
            for (int j = 0; j < 4; ++j)
                acc[i][j] = __builtin_amdgcn_mfma_f32_16x16x32_bf16(
                    a[i], b[j], acc[i][j], 0, 0, 0);
    }

    #pragma unroll
    for (int j = 0; j < 4; ++j) {
        int mrow = m0 + j * 16 + r;
        float* rowp = logits + (size_t)mrow * KCLS;

        // floatx4 (ext-vector) nontemporal stores: 4 consecutive classes per
        // lane. KCLS % 4 == 0 so a store is either fully valid or fully pad.
        #pragma unroll
        for (int i = 0; i < 4; ++i) {
            int nb = n0 + i * 16 + quad * 4;
            if (nb < KCLS)
                __builtin_nontemporal_store(acc[i][j], (floatx4*)(rowp + nb));
        }

        if constexpr (PART) {
            // wave-wide (64-class) max+sumexp for this batch row.
            // every quad has i==0 valid (worst pad block starts at 49984),
            // so mx is finite before the shuffles.
            float mx = -INFINITY;
            #pragma unroll
            for (int i = 0; i < 4; ++i) {
                bool ok = (n0 + i * 16 + quad * 4) < KCLS;
                #pragma unroll
                for (int reg = 0; reg < 4; ++reg) {
                    float v = ok ? acc[i][j][reg] : -INFINITY;
                    mx = fmaxf(mx, v);
                }
            }
            mx = fmaxf(mx, __shfl_xor(mx, 16));
            mx = fmaxf(mx, __shfl_xor(mx, 32));
            float s = 0.f;
            #pragma unroll
            for (int i = 0; i < 4; ++i) {
                bool ok = (n0 + i * 16 + quad * 4) < KCLS;
                #pragma unroll
                for (int reg = 0; reg < 4; ++reg) {
                    float v = ok ? acc[i][j][reg] : -INFINITY;
                    s += __expf(v - mx);    // exp(-inf) = 0 for pad
                }
            }
            s += __shfl_xor(s, 16);
            s += __shfl_xor(s, 32);
            if (quad == 0)
                part[(size_t)mrow * NBP + blockIdx.y * 2 + (wave & 1)]
                    = make_float2(mx, s);
        }
    }
}

// ---------------------------------------------------------------------------
// Kernel 3 (fused path): reduce NBP=782 (m,s) partials per row -> lse -> loss.
// One wave per row; ~6.4 MB total read (vs 204.8 MB logits re-read).
__global__ __launch_bounds__(256) void lsereduce_kernel(
    const float2* __restrict__ part, const float* __restrict__ logits,
    const int* __restrict__ y, float* __restrict__ loss)
{
    int b = blockIdx.x * 4 + (threadIdx.x >> 6);
    int lane = threadIdx.x & 63;
    const float2* pr = part + (size_t)b * NBP;

    float m = -INFINITY, s = 0.f;
    for (int i = lane; i < NBP; i += 64) {   // every lane gets >=12 -> m finite
        float2 pv = pr[i];
        if (pv.x > m) {
            s = s * __expf(m - pv.x) + pv.y;
            m = pv.x;
        } else {
            s += pv.y * __expf(pv.x - m);
        }
    }
    #pragma unroll
    for (int off = 32; off; off >>= 1) {
        float m2 = __shfl_xor(m, off);
        float s2 = __shfl_xor(s, off);
        float M = fmaxf(m, m2);
        s = s * __expf(m - M) + s2 * __expf(m2 - M);
        m = M;
    }
    if (lane == 0) {
        float lse = m + __logf(s);
        float ly = logits[(size_t)b * KCLS + y[b]];
        atomicAdd(loss, (lse - ly) * (1.0f / BATCH));
    }
}

// ---------------------------------------------------------------------------
// Fallback (workspace too small for partials): per-row logsumexp over logits.
__global__ __launch_bounds__(256) void lse_kernel(
    const float* __restrict__ logits, const int* __restrict__ y,
    float* __restrict__ loss)
{
    int b = blockIdx.x;
    const float* row = logits + (size_t)b * KCLS;
    float m = -INFINITY, s = 0.f;

    auto upd = [&](float v) {
        if (v <= m) {
            s += __expf(v - m);
        } else {
            s = s * __expf(m - v) + 1.f;
            m = v;
        }
    };

    if (threadIdx.x < 3) upd(row[threadIdx.x]);
    const float4* rv = (const float4*)(row + 3);
    for (int i = threadIdx.x; i < 12499; i += 256) {
        float4 v = rv[i];
        upd(v.x); upd(v.y); upd(v.z); upd(v.w);
    }
    if (threadIdx.x == 3) upd(row[49999]);

    #pragma unroll
    for (int off = 32; off > 0; off >>= 1) {
        float m2 = __shfl_down(m, off);
        float s2 = __shfl_down(s, off);
        float M = fmaxf(m, m2);
        s = s * __expf(m - M) + s2 * __expf(m2 - M);
        m = M;
    }
    __shared__ float sm[4], ss[4];
    int w = threadIdx.x >> 6, l = threadIdx.x & 63;
    if (l == 0) { sm[w] = m; ss[w] = s; }
    __syncthreads();
    if (threadIdx.x == 0) {
        m = sm[0]; s = ss[0];
        #pragma unroll
        for (int i = 1; i < 4; ++i) {
            float M = fmaxf(m, sm[i]);
            s = s * __expf(m - M) + ss[i] * __expf(sm[i] - M);
            m = M;
        }
        float lse = m + __logf(s);
        float ly = row[y[b]];
        atomicAdd(loss, (lse - ly) * (1.0f / BATCH));
    }
}

// ---------------------------------------------------------------------------
extern "C" void kernel_launch(void* const* d_in, const int* in_sizes, int n_in,
                              void* d_out, int out_size, void* d_ws, size_t ws_size,
                              hipStream_t stream)
{
    const float* weights  = (const float*)d_in[0];   // [65536][128]
    const float* x        = (const float*)d_in[1];   // [1024][128]
    const int*   y        = (const int*)d_in[2];     // [1024]
    const int*   path_idx = (const int*)d_in[3];     // [50000][16]
    const int*   path_len = (const int*)d_in[4];     // [50000]

    float* out    = (float*)d_out;
    float* loss   = out;                                  // [1]
    float* logits = out + 1;                              // [1024][50000]
    float* aw     = out + 1 + (size_t)BATCH * KCLS;       // [50000][128]

    size_t awb_sz  = (size_t)KP * DIM * sizeof(unsigned short);     // 12.8 MB
    size_t xb_sz   = (size_t)BATCH * DIM * sizeof(unsigned short);  // 0.26 MB
    size_t part_sz = (size_t)BATCH * NBP * sizeof(float2);          // 6.4 MB

    unsigned short* awb = (unsigned short*)d_ws;
    unsigned short* xb  = awb + (size_t)KP * DIM;
    float2* part = (float2*)((char*)d_ws + awb_sz + xb_sz);
    bool fused = ws_size >= awb_sz + xb_sz + part_sz;

    (void)hipMemsetAsync(loss, 0, sizeof(float), stream);

    aw_kernel<<<CLS_BLOCKS + XB_BLOCKS, 256, 0, stream>>>(
        weights, path_idx, path_len, aw, awb, x, xb);

    if (fused) {
        gemm_kernel<true><<<dim3(BATCH / 128, NBLK_N), 256, 0, stream>>>(
            xb, awb, logits, part);
        lsereduce_kernel<<<BATCH / 4, 256, 0, stream>>>(part, logits, y, loss);
    } else {
        gemm_kernel<false><<<dim3(BATCH / 128, NBLK_N), 256, 0, stream>>>(
            xb, awb, logits, nullptr);
        lse_kernel<<<BATCH, 256, 0, stream>>>(logits, y, loss);
    }
}

// Round 5
// 380.220 us; speedup vs baseline: 1.2667x; 1.2667x over previous
//
#include <hip/hip_runtime.h>
#include <math.h>

#define KCLS  50000
#define KP    50048   // KCLS padded to multiple of 128 for the GEMM class dim
#define DIM   128
#define BATCH 1024
#define MAXD  16

#define NBLK_N   (KP / 128)       // 391 column blocks in the GEMM
#define NBP      (NBLK_N * 2)     // 782 partial (m,s) pairs per row (2 col-waves/block)
#define CLS_BLOCKS (KP / 4)       // 12512 aw blocks (4 classes per 256-thr block)
#define XB_BLOCKS  (BATCH * DIM / 1024)  // 128 folded x-conversion blocks

typedef __attribute__((ext_vector_type(8))) short short8;
typedef __attribute__((ext_vector_type(4))) float floatx4;

// round-to-nearest-even float -> bf16 bits (inputs are finite)
__device__ __forceinline__ unsigned short f2bf(float f) {
    unsigned u = __float_as_uint(f);
    u += 0x7fffu + ((u >> 16) & 1u);
    return (unsigned short)(u >> 16);
}

// ---------------------------------------------------------------------------
// Kernel 1: added_weights[k] = weights[k] + sum_{p<len} weights[path_idx[k,p]]
// ONE class per 64-lane wave (float2/lane = one 512B row) so the path loop
// trip count is wave-uniform. 4-deep unrolled path loop: 4 row-loads in
// flight (avg len = 7.5, so main loop runs ~2 iters with full MLP).
// Emits bf16 copy (pad rows zeroed). Blocks >= CLS_BLOCKS convert x -> bf16.
__global__ __launch_bounds__(256) void aw_kernel(
    const float* __restrict__ weights, const int* __restrict__ path_idx,
    const int* __restrict__ path_len, float* __restrict__ aw,
    unsigned short* __restrict__ awb,
    const float* __restrict__ x, unsigned short* __restrict__ xb)
{
    int t = threadIdx.x;

    if (blockIdx.x >= CLS_BLOCKS) {   // folded x fp32->bf16 (131072 elements)
        int i = ((blockIdx.x - CLS_BLOCKS) * 256 + t) * 4;
        float4 v = *(const float4*)(x + i);
        ushort4 hv = { f2bf(v.x), f2bf(v.y), f2bf(v.z), f2bf(v.w) };
        *(ushort4*)(xb + i) = hv;
        return;
    }

    int w = t >> 6, lane = t & 63;
    int k = blockIdx.x * 4 + w;
    int col = lane * 2;

    if (k >= KCLS) {                  // zero-fill bf16 pad rows [KCLS, KP)
        ushort2 z; z.x = 0; z.y = 0;
        *(ushort2*)(awb + (size_t)k * DIM + col) = z;
        return;
    }

    float2 acc = *(const float2*)(weights + (size_t)k * DIM + col);
    int len = path_len[k];
    const int* pp = path_idx + (size_t)k * MAXD;

    int p = 0;
    for (; p + 4 <= len; p += 4) {    // 4 row loads in flight
        int i0 = pp[p], i1 = pp[p + 1], i2 = pp[p + 2], i3 = pp[p + 3];
        float2 a = *(const float2*)(weights + (size_t)i0 * DIM + col);
        float2 b = *(const float2*)(weights + (size_t)i1 * DIM + col);
        float2 c = *(const float2*)(weights + (size_t)i2 * DIM + col);
        float2 d = *(const float2*)(weights + (size_t)i3 * DIM + col);
        acc.x += (a.x + b.x) + (c.x + d.x);
        acc.y += (a.y + b.y) + (c.y + d.y);
    }
    for (; p < len; ++p) {
        int i0 = pp[p];
        float2 a = *(const float2*)(weights + (size_t)i0 * DIM + col);
        acc.x += a.x;
        acc.y += a.y;
    }

    *(float2*)(aw + (size_t)k * DIM + col) = acc;   // output (never re-read)
    ushort2 hv; hv.x = f2bf(acc.x); hv.y = f2bf(acc.y);
    *(ushort2*)(awb + (size_t)k * DIM + col) = hv;
}

// ---------------------------------------------------------------------------
// Kernel 2: logits = Xb · Wb^T via bf16 MFMA 16x16x32, SWAPPED operands:
// A = W-tile (classes = C rows), B = X-tile (batch = C cols). C/D layout
// (col=lane&15, row=quad*4+reg) then gives each lane 4 CONSECUTIVE classes
// in one batch row -> one floatx4 store per tile.
// Stores go THROUGH L2 (plain, not nontemporal): round-4 counters showed NT
// stores cost 1.84x WRITE_SIZE (387 MB vs 211 MB logical) — the wave's 64B
// row segments only merge into full 128B lines inside L2. NT bypassed that
// and halved effective write BW (gemm 208us @ 2.1 TB/s, nothing saturated).
// Grid: x = M-blocks (8, fastest) so the 8 blocks sharing one Wb tile
// dispatch back-to-back -> Wb stays L2-resident across them.
// PART: fused LSE partials; per batch row the wave reduce is 16 lane-local
// values + 2 shfl_xor (across quads).
template<bool PART>
__global__ __launch_bounds__(256) void gemm_kernel(
    const unsigned short* __restrict__ Xb,   // [BATCH][DIM] bf16
    const unsigned short* __restrict__ Wb,   // [KP][DIM] bf16
    float* __restrict__ logits,              // [BATCH][KCLS]
    float2* __restrict__ part)               // [BATCH][NBP] (m, sumexp)
{
    int tid = threadIdx.x;
    int wave = tid >> 6, lane = tid & 63;
    int r = lane & 15, quad = lane >> 4;
    int m0 = blockIdx.x * 128 + (wave >> 1) * 64;   // batch rows
    int n0 = blockIdx.y * 128 + (wave & 1) * 64;    // class cols

    const unsigned short* wp = Wb + (size_t)(n0 + r) * DIM + quad * 8;  // A
    const unsigned short* xp = Xb + (size_t)(m0 + r) * DIM + quad * 8;  // B

    floatx4 acc[4][4];   // [class-tile i][batch-tile j]
    #pragma unroll
    for (int i = 0; i < 4; ++i)
        #pragma unroll
        for (int j = 0; j < 4; ++j)
            acc[i][j] = (floatx4){0.f, 0.f, 0.f, 0.f};

    #pragma unroll
    for (int kk = 0; kk < 4; ++kk) {
        short8 a[4], b[4];
        #pragma unroll
        for (int i = 0; i < 4; ++i)
            a[i] = *(const short8*)(wp + (size_t)(i * 16) * DIM + kk * 32);
        #pragma unroll
        for (int j = 0; j < 4; ++j)
            b[j] = *(const short8*)(xp + (size_t)(j * 16) * DIM + kk * 32);
        #pragma unroll
        for (int i = 0; i < 4; ++i)
            #pragma unroll
            for (int j = 0; j < 4; ++j)
                acc[i][j] = __builtin_amdgcn_mfma_f32_16x16x32_bf16(
                    a[i], b[j], acc[i][j], 0, 0, 0);
    }

    #pragma unroll
    for (int j = 0; j < 4; ++j) {
        int mrow = m0 + j * 16 + r;
        float* rowp = logits + (size_t)mrow * KCLS;

        // plain floatx4 stores: 4 consecutive classes per lane; the i-loop
        // covers 256B contiguous per row, merged to full lines in L2.
        // KCLS % 4 == 0 so a store is either fully valid or fully pad.
        #pragma unroll
        for (int i = 0; i < 4; ++i) {
            int nb = n0 + i * 16 + quad * 4;
            if (nb < KCLS)
                *(floatx4*)(rowp + nb) = acc[i][j];
        }

        if constexpr (PART) {
            // wave-wide (64-class) max+sumexp for this batch row.
            // every quad has i==0 valid (worst pad block starts at 49984),
            // so mx is finite before the shuffles.
            float mx = -INFINITY;
            #pragma unroll
            for (int i = 0; i < 4; ++i) {
                bool ok = (n0 + i * 16 + quad * 4) < KCLS;
                #pragma unroll
                for (int reg = 0; reg < 4; ++reg) {
                    float v = ok ? acc[i][j][reg] : -INFINITY;
                    mx = fmaxf(mx, v);
                }
            }
            mx = fmaxf(mx, __shfl_xor(mx, 16));
            mx = fmaxf(mx, __shfl_xor(mx, 32));
            float s = 0.f;
            #pragma unroll
            for (int i = 0; i < 4; ++i) {
                bool ok = (n0 + i * 16 + quad * 4) < KCLS;
                #pragma unroll
                for (int reg = 0; reg < 4; ++reg) {
                    float v = ok ? acc[i][j][reg] : -INFINITY;
                    s += __expf(v - mx);    // exp(-inf) = 0 for pad
                }
            }
            s += __shfl_xor(s, 16);
            s += __shfl_xor(s, 32);
            if (quad == 0)
                part[(size_t)mrow * NBP + blockIdx.y * 2 + (wave & 1)]
                    = make_float2(mx, s);
        }
    }
}

// ---------------------------------------------------------------------------
// Kernel 3 (fused path): reduce NBP=782 (m,s) partials per row -> lse -> loss.
// One wave per row; ~6.4 MB total read (vs 204.8 MB logits re-read).
__global__ __launch_bounds__(256) void lsereduce_kernel(
    const float2* __restrict__ part, const float* __restrict__ logits,
    const int* __restrict__ y, float* __restrict__ loss)
{
    int b = blockIdx.x * 4 + (threadIdx.x >> 6);
    int lane = threadIdx.x & 63;
    const float2* pr = part + (size_t)b * NBP;

    float m = -INFINITY, s = 0.f;
    for (int i = lane; i < NBP; i += 64) {   // every lane gets >=12 -> m finite
        float2 pv = pr[i];
        if (pv.x > m) {
            s = s * __expf(m - pv.x) + pv.y;
            m = pv.x;
        } else {
            s += pv.y * __expf(pv.x - m);
        }
    }
    #pragma unroll
    for (int off = 32; off; off >>= 1) {
        float m2 = __shfl_xor(m, off);
        float s2 = __shfl_xor(s, off);
        float M = fmaxf(m, m2);
        s = s * __expf(m - M) + s2 * __expf(m2 - M);
        m = M;
    }
    if (lane == 0) {
        float lse = m + __logf(s);
        float ly = logits[(size_t)b * KCLS + y[b]];
        atomicAdd(loss, (lse - ly) * (1.0f / BATCH));
    }
}

// ---------------------------------------------------------------------------
// Fallback (workspace too small for partials): per-row logsumexp over logits.
__global__ __launch_bounds__(256) void lse_kernel(
    const float* __restrict__ logits, const int* __restrict__ y,
    float* __restrict__ loss)
{
    int b = blockIdx.x;
    const float* row = logits + (size_t)b * KCLS;
    float m = -INFINITY, s = 0.f;

    auto upd = [&](float v) {
        if (v <= m) {
            s += __expf(v - m);
        } else {
            s = s * __expf(m - v) + 1.f;
            m = v;
        }
    };

    if (threadIdx.x < 3) upd(row[threadIdx.x]);
    const float4* rv = (const float4*)(row + 3);
    for (int i = threadIdx.x; i < 12499; i += 256) {
        float4 v = rv[i];
        upd(v.x); upd(v.y); upd(v.z); upd(v.w);
    }
    if (threadIdx.x == 3) upd(row[49999]);

    #pragma unroll
    for (int off = 32; off > 0; off >>= 1) {
        float m2 = __shfl_down(m, off);
        float s2 = __shfl_down(s, off);
        float M = fmaxf(m, m2);
        s = s * __expf(m - M) + s2 * __expf(m2 - M);
        m = M;
    }
    __shared__ float sm[4], ss[4];
    int w = threadIdx.x >> 6, l = threadIdx.x & 63;
    if (l == 0) { sm[w] = m; ss[w] = s; }
    __syncthreads();
    if (threadIdx.x == 0) {
        m = sm[0]; s = ss[0];
        #pragma unroll
        for (int i = 1; i < 4; ++i) {
            float M = fmaxf(m, sm[i]);
            s = s * __expf(m - M) + ss[i] * __expf(sm[i] - M);
            m = M;
        }
        float lse = m + __logf(s);
        float ly = row[y[b]];
        atomicAdd(loss, (lse - ly) * (1.0f / BATCH));
    }
}

// ---------------------------------------------------------------------------
extern "C" void kernel_launch(void* const* d_in, const int* in_sizes, int n_in,
                              void* d_out, int out_size, void* d_ws, size_t ws_size,
                              hipStream_t stream)
{
    const float* weights  = (const float*)d_in[0];   // [65536][128]
    const float* x        = (const float*)d_in[1];   // [1024][128]
    const int*   y        = (const int*)d_in[2];     // [1024]
    const int*   path_idx = (const int*)d_in[3];     // [50000][16]
    const int*   path_len = (const int*)d_in[4];     // [50000]

    float* out    = (float*)d_out;
    float* loss   = out;                                  // [1]
    float* logits = out + 1;                              // [1024][50000]
    float* aw     = out + 1 + (size_t)BATCH * KCLS;       // [50000][128]

    size_t awb_sz  = (size_t)KP * DIM * sizeof(unsigned short);     // 12.8 MB
    size_t xb_sz   = (size_t)BATCH * DIM * sizeof(unsigned short);  // 0.26 MB
    size_t part_sz = (size_t)BATCH * NBP * sizeof(float2);          // 6.4 MB

    unsigned short* awb = (unsigned short*)d_ws;
    unsigned short* xb  = awb + (size_t)KP * DIM;
    float2* part = (float2*)((char*)d_ws + awb_sz + xb_sz);
    bool fused = ws_size >= awb_sz + xb_sz + part_sz;

    (void)hipMemsetAsync(loss, 0, sizeof(float), stream);

    aw_kernel<<<CLS_BLOCKS + XB_BLOCKS, 256, 0, stream>>>(
        weights, path_idx, path_len, aw, awb, x, xb);

    if (fused) {
        gemm_kernel<true><<<dim3(BATCH / 128, NBLK_N), 256, 0, stream>>>(
            xb, awb, logits, part);
        lsereduce_kernel<<<BATCH / 4, 256, 0, stream>>>(part, logits, y, loss);
    } else {
        gemm_kernel<false><<<dim3(BATCH / 128, NBLK_N), 256, 0, stream>>>(
            xb, awb, logits, nullptr);
        lse_kernel<<<BATCH, 256, 0, stream>>>(logits, y, loss);
    }
}